// Round 2
// 553.181 us; speedup vs baseline: 1.0259x; 1.0259x over previous
//
#include <hip/hip_runtime.h>

#define NN 100000
#define EE 1600000
#define ELLW 64   // max in-degree; Poisson(16) over 100K nodes -> max ~40, 64 safe
#define GEMMN ((NN + 31) / 32)          // 3125 gemm blocks (32-row tiles)
#define BQ ((EE / 4 + 511) / 512)       // 782 build blocks, 8 edges/thread (2x int4)
#define GRID_BG (BQ * 5)                // interleave 1 build : 4 gemm

typedef int iv4 __attribute__((ext_vector_type(4)));   // native vector: NT-load legal

// bf16 round-to-nearest-even pack of two floats -> (lo=a, hi=b)
__device__ __forceinline__ unsigned int pack_bf2(float a, float b) {
    unsigned int ua = __float_as_uint(a);
    ua += 0x7FFFu + ((ua >> 16) & 1u);
    unsigned int ub = __float_as_uint(b);
    ub += 0x7FFFu + ((ub >> 16) & 1u);
    return (ua >> 16) | (ub & 0xFFFF0000u);
}

// ---------------- GEMM body: Ybf16[32 rows x 128] = X @ W, 256 threads, 16 KB LDS ----
__device__ __forceinline__ void gemm128_body(const float* __restrict__ X,
                                             const float* __restrict__ W, unsigned int* __restrict__ Y,
                                             int row0, int tid, float* Xs) {
    const float4* X4 = (const float4*)X;
#pragma unroll
    for (int idx = tid; idx < 1024; idx += 256) {
        int r = idx & 31, c4 = idx >> 5;
        int row = row0 + r;
        float4 v = X4[(size_t)row * 32 + c4];
        Xs[(c4 * 4 + 0) * 32 + r] = v.x;
        Xs[(c4 * 4 + 1) * 32 + r] = v.y;
        Xs[(c4 * 4 + 2) * 32 + r] = v.z;
        Xs[(c4 * 4 + 3) * 32 + r] = v.w;
    }
    __syncthreads();
    int cg = tid & 31;   // cols 4cg..4cg+3
    int rg = tid >> 5;   // rows 4rg..4rg+3
    float a[4][4];
#pragma unroll
    for (int r = 0; r < 4; ++r)
#pragma unroll
        for (int c = 0; c < 4; ++c) a[r][c] = 0.f;
    const float4* W4 = (const float4*)W;
#pragma unroll 4
    for (int k = 0; k < 128; ++k) {
        float4 xv = *(const float4*)&Xs[k * 32 + rg * 4];
        float4 wv = W4[k * 32 + cg];
        float xr[4] = {xv.x, xv.y, xv.z, xv.w};
        float wc[4] = {wv.x, wv.y, wv.z, wv.w};
#pragma unroll
        for (int r = 0; r < 4; ++r)
#pragma unroll
            for (int c = 0; c < 4; ++c) a[r][c] = fmaf(xr[r], wc[c], a[r][c]);
    }
    int rbase = row0 + rg * 4;
    uint2* Y2 = (uint2*)Y;   // 32 uint2 per 128-col bf16 row
#pragma unroll
    for (int r = 0; r < 4; ++r) {
        Y2[(size_t)(rbase + r) * 32 + cg] =
            make_uint2(pack_bf2(a[r][0], a[r][1]), pack_bf2(a[r][2], a[r][3]));
    }
}

// ---------------- fused: interleaved GEMM0 + single-pass ELL build ----------------
// De-partitioned: each edge processed exactly ONCE (8 edges/thread, int4 NT loads,
// 8 independent atomic chains per thread for latency hiding). Device atomics execute
// at the shared coherence point regardless of issuing XCD, so the old 8x XCD
// partitioning only multiplied wave count and edge fetch. Interleave 1:4 with GEMM0
// blocks so VALU work hides under atomic latency for the whole kernel.
__global__ __launch_bounds__(256) void k_build_gemm0(const int* __restrict__ src, const int* __restrict__ dst,
                                                     int* __restrict__ din, int* __restrict__ dout,
                                                     int* __restrict__ ell,
                                                     const float* __restrict__ X, const float* __restrict__ W,
                                                     unsigned int* __restrict__ Y) {
    __shared__ float Xs[128 * 32];
    int tid = threadIdx.x;
    int q = blockIdx.x / 5, rem = blockIdx.x % 5;
    if (rem) {   // GEMM block
        int g = q * 4 + (rem - 1);
        if (g < GEMMN) gemm128_body(X, W, Y, g * 32, tid, Xs);
        return;
    }
    const iv4* s4p = (const iv4*)src;
    const iv4* d4p = (const iv4*)dst;
    const int n4 = EE / 4;
#pragma unroll
    for (int h = 0; h < 2; ++h) {
        int i4 = q * 512 + h * 256 + tid;
        if (i4 < n4) {
            iv4 s4 = __builtin_nontemporal_load(&s4p[i4]);
            iv4 d4 = __builtin_nontemporal_load(&d4p[i4]);
            int ss[4] = {s4.x, s4.y, s4.z, s4.w};
            int dd[4] = {d4.x, d4.y, d4.z, d4.w};
#pragma unroll
            for (int k = 0; k < 4; ++k) {
                int p = atomicAdd(&din[dd[k]], 1);
                if (p < ELLW) ell[(size_t)dd[k] * ELLW + p] = ss[k];
            }
#pragma unroll
            for (int k = 0; k < 4; ++k) atomicAdd(&dout[ss[k]], 1);
        }
    }
}

// ---------------- fused gather + GEMM128 (layer boundary) ----------------
// Per 32-row tile: gather neighbors from bf16 h (optionally per-neighbor so-scale),
// apply si/bias/relu + so pre-scale in registers, stage to LDS (stride 36: float4
// reads stay 16B-aligned broadcasts; transpose writes only 16-way on 16 stores/wave),
// then GEMM @ W[128x128] -> bf16 Y. Eliminates the 51.2MB f32 agg round-trip.
__global__ __launch_bounds__(256) void k_gathergemm128(const unsigned int* __restrict__ h,
                                                       const int* __restrict__ din, const int* __restrict__ dout,
                                                       const int* __restrict__ ell,
                                                       const float* __restrict__ bias,
                                                       const float* __restrict__ W,
                                                       unsigned int* __restrict__ Y, int so_mode) {
    __shared__ float Xs[128 * 36];
    int tid = threadIdx.x;
    int wv = tid >> 6, lane = tid & 63;
    int row0 = blockIdx.x * 32;
    float2 bb = ((const float2*)bias)[lane];
    for (int j8 = 0; j8 < 8; ++j8) {
        int r = wv * 8 + j8;
        int v = row0 + r;       // N = 3125*32 exactly, no bounds needed
        int dv = din[v];
        int cnt = min(dv, ELLW);
        int cl = ell[(size_t)v * ELLW + lane];
        // ELL slots >= cnt are UNINITIALIZED -> clamp before any deref
        int cls = (lane < cnt) ? cl : 0;
        float scl = 1.f;
        if (so_mode) scl = rsqrtf((float)max(1, dout[cls]));
        float sx = 0.f, sy = 0.f;
        for (int j = 0; j < cnt; j += 8) {
            int cc[8]; float mk[8]; unsigned int t[8];
#pragma unroll
            for (int k = 0; k < 8; ++k) {
                int jj = j + k;
                int jc = jj < cnt ? jj : cnt - 1;
                cc[k] = __shfl(cls, jc);
                float sw = so_mode ? __shfl(scl, jc) : 1.f;
                mk[k] = (jj < cnt) ? sw : 0.f;
            }
#pragma unroll
            for (int k = 0; k < 8; ++k) t[k] = h[(size_t)cc[k] * 64 + lane];
#pragma unroll
            for (int k = 0; k < 8; ++k) {
                float x = __uint_as_float(t[k] << 16);
                float y = __uint_as_float(t[k] & 0xFFFF0000u);
                sx = fmaf(mk[k], x, sx);
                sy = fmaf(mk[k], y, sy);
            }
        }
        float si = rsqrtf((float)max(1, dv));
        float so = rsqrtf((float)max(1, dout[v]));
        float ox = fmaxf(sx * si + bb.x, 0.f) * so;
        float oy = fmaxf(sy * si + bb.y, 0.f) * so;
        Xs[(2 * lane) * 36 + r] = ox;
        Xs[(2 * lane + 1) * 36 + r] = oy;
    }
    __syncthreads();
    int cg = tid & 31, rg = tid >> 5;
    float a[4][4];
#pragma unroll
    for (int r = 0; r < 4; ++r)
#pragma unroll
        for (int c = 0; c < 4; ++c) a[r][c] = 0.f;
    const float4* W4 = (const float4*)W;
#pragma unroll 4
    for (int k = 0; k < 128; ++k) {
        float4 xv = *(const float4*)&Xs[k * 36 + rg * 4];
        float4 wv4 = W4[k * 32 + cg];
        float xr[4] = {xv.x, xv.y, xv.z, xv.w};
        float wc[4] = {wv4.x, wv4.y, wv4.z, wv4.w};
#pragma unroll
        for (int r = 0; r < 4; ++r)
#pragma unroll
            for (int c = 0; c < 4; ++c) a[r][c] = fmaf(xr[r], wc[c], a[r][c]);
    }
    int rbase = row0 + rg * 4;
    uint2* Y2 = (uint2*)Y;
#pragma unroll
    for (int r = 0; r < 4; ++r) {
        Y2[(size_t)(rbase + r) * 32 + cg] =
            make_uint2(pack_bf2(a[r][0], a[r][1]), pack_bf2(a[r][2], a[r][3]));
    }
}

// ---------------- fused gather + GEMM[128x40] (layer 2 pre-gather transform) --------
// Gather (so already folded into h rows -> so_mode=0 semantics), si/b1/relu + so
// pre-scale, GEMM @ W2[128x40] -> bf16 padded-128B rows for the final gather.
__global__ __launch_bounds__(256) void k_gathergemm40(const unsigned int* __restrict__ h,
                                                      const int* __restrict__ din, const int* __restrict__ dout,
                                                      const int* __restrict__ ell,
                                                      const float* __restrict__ bias,
                                                      const float* __restrict__ W,
                                                      unsigned int* __restrict__ Y) {
    __shared__ float Xs[128 * 36];
    __shared__ float Os[32 * 40];
    int tid = threadIdx.x;
    int wv = tid >> 6, lane = tid & 63;
    int row0 = blockIdx.x * 32;
    float2 bb = ((const float2*)bias)[lane];
    for (int j8 = 0; j8 < 8; ++j8) {
        int r = wv * 8 + j8;
        int v = row0 + r;
        int dv = din[v];
        int cnt = min(dv, ELLW);
        int cl = ell[(size_t)v * ELLW + lane];
        int cls = (lane < cnt) ? cl : 0;
        float sx = 0.f, sy = 0.f;
        for (int j = 0; j < cnt; j += 8) {
            int cc[8]; float mk[8]; unsigned int t[8];
#pragma unroll
            for (int k = 0; k < 8; ++k) {
                int jj = j + k;
                cc[k] = __shfl(cls, jj < cnt ? jj : cnt - 1);
                mk[k] = (jj < cnt) ? 1.f : 0.f;
            }
#pragma unroll
            for (int k = 0; k < 8; ++k) t[k] = h[(size_t)cc[k] * 64 + lane];
#pragma unroll
            for (int k = 0; k < 8; ++k) {
                float x = __uint_as_float(t[k] << 16);
                float y = __uint_as_float(t[k] & 0xFFFF0000u);
                sx = fmaf(mk[k], x, sx);
                sy = fmaf(mk[k], y, sy);
            }
        }
        float si = rsqrtf((float)max(1, dv));
        float so = rsqrtf((float)max(1, dout[v]));
        float ox = fmaxf(sx * si + bb.x, 0.f) * so;
        float oy = fmaxf(sy * si + bb.y, 0.f) * so;
        Xs[(2 * lane) * 36 + r] = ox;
        Xs[(2 * lane + 1) * 36 + r] = oy;
    }
    __syncthreads();
    // gemm: thread = (row rg, 5-col group cg). W2 is 20KB -> L1-resident broadcasts.
    int rg = tid >> 3;       // 32 rows
    int cg = tid & 7;        // 8 groups x 5 cols
    float a[5] = {0.f, 0.f, 0.f, 0.f, 0.f};
    for (int k = 0; k < 128; ++k) {
        float x = Xs[k * 36 + rg];
#pragma unroll
        for (int c = 0; c < 5; ++c) a[c] = fmaf(x, W[k * 40 + cg * 5 + c], a[c]);
    }
#pragma unroll
    for (int c = 0; c < 5; ++c) Os[rg * 40 + cg * 5 + c] = a[c];
    __syncthreads();
    for (int i = tid; i < 640; i += 256) {
        int row = i / 20, pj = i % 20;
        Y[(size_t)(row0 + row) * 32 + pj] = pack_bf2(Os[row * 40 + 2 * pj], Os[row * 40 + 2 * pj + 1]);
    }
}

// ---------------- gather-aggregate (ELL), 40 cols bf16 padded-128B rows (final layer) ----
__global__ __launch_bounds__(256) void k_gather40(const unsigned short* __restrict__ h, const int* __restrict__ din,
                                                  const int* __restrict__ ell,
                                                  const float* __restrict__ b, float* __restrict__ out, int n) {
    int wv = threadIdx.x >> 6, lane = threadIdx.x & 63;
    int v = blockIdx.x * 4 + wv;
    if (v >= n) return;
    int dv = din[v];
    int cnt = min(dv, ELLW);
    int cl = ell[(size_t)v * ELLW + lane];
    int cls = (lane < cnt) ? cl : 0;
    float s = 0.f;
    for (int j = 0; j < cnt; j += 8) {
        int cc[8]; float mk[8]; unsigned short t[8];
#pragma unroll
        for (int k = 0; k < 8; ++k) {
            int jj = j + k;
            cc[k] = __shfl(cls, jj < cnt ? jj : cnt - 1);
            mk[k] = (jj < cnt) ? 1.f : 0.f;
        }
        if (lane < 40) {
#pragma unroll
            for (int k = 0; k < 8; ++k) t[k] = h[(size_t)cc[k] * 64 + lane];  // 64-short rows = 128 B
#pragma unroll
            for (int k = 0; k < 8; ++k)
                s = fmaf(mk[k], __uint_as_float((unsigned int)t[k] << 16), s);
        }
    }
    if (lane < 40) {
        out[(size_t)v * 40 + lane] = s * rsqrtf((float)max(1, dv)) + b[lane];
    }
}

extern "C" void kernel_launch(void* const* d_in, const int* in_sizes, int n_in,
                              void* d_out, int out_size, void* d_ws, size_t ws_size,
                              hipStream_t stream) {
    const float* feat = (const float*)d_in[0];
    const int*   src  = (const int*)d_in[1];
    const int*   dst  = (const int*)d_in[2];
    const float* W0   = (const float*)d_in[3];
    const float* b0   = (const float*)d_in[4];
    const float* W1   = (const float*)d_in[5];
    const float* b1   = (const float*)d_in[6];
    const float* W2   = (const float*)d_in[7];
    const float* b2   = (const float*)d_in[8];
    float* out = (float*)d_out;

    char* w = (char*)d_ws;
    int*   din       = (int*)w;    w += (size_t)NN * 4;
    int*   dout      = (int*)w;    w += (size_t)NN * 4;
    int*   ell       = (int*)w;    w += (size_t)NN * ELLW * 4;        // 25.6 MB
    unsigned int* h2 = (unsigned int*)w; w += (size_t)NN * 128 * 2;   // bf16 rows, 25.6 MB
    unsigned int* h2b = (unsigned int*)w; w += (size_t)NN * 128 * 2;  // bf16 rows, 25.6 MB
    unsigned int* h40 = (unsigned int*)w; w += (size_t)NN * 32 * 4;   // bf16 40-col rows padded to 128 B

    // zero the two degree counters (contiguous at base)
    (void)hipMemsetAsync(d_ws, 0, (size_t)NN * 8, stream);

    // fused: interleaved GEMM0 (unscaled feat@W0 -> h2) + single-pass ELL/degree build
    k_build_gemm0<<<GRID_BG, 256, 0, stream>>>(src, dst, din, dout, ell, feat, W0, h2);
    // layer 0 gather (per-neighbor so, si, b0, relu) + so-prescale + GEMM W1 -> h2b
    k_gathergemm128<<<GEMMN, 256, 0, stream>>>(h2, din, dout, ell, b0, W1, h2b, 1);
    // layer 1 gather (so folded in h2b, si, b1, relu) + so-prescale + GEMM W2 -> h40
    k_gathergemm40<<<GEMMN, 256, 0, stream>>>(h2b, din, dout, ell, b1, W2, h40);
    // final gather writes d_out
    k_gather40<<<(NN + 3) / 4, 256, 0, stream>>>((const unsigned short*)h40, din, ell, b2, out, NN);
}

// Round 3
// 491.911 us; speedup vs baseline: 1.1537x; 1.1246x over previous
//
#include <hip/hip_runtime.h>

#define NN 100000
#define EE 1600000
#define ELLW 64   // max in-degree; Poisson(16) over 100K nodes -> max ~45, 64 safe
#define GEMMN ((NN + 31) / 32)          // 3125 gemm blocks (32-row tiles)
#define BQ ((EE / 4 + 511) / 512)       // 782 build blocks, 8 edges/thread (2x int4)
#define GRID_BG (BQ * 5)                // interleave 1 build : 4 gemm

#define NBKT 196                        // ceil(100000 / 512) buckets of 512 nodes
#define BSH 9                           // bucket = node >> 9
#define CAPD 10240                      // staged edges per dst-bucket (mean 8192 + 22 sigma)
#define CAPS 10240                      // staged edges per src-bucket

typedef int iv4 __attribute__((ext_vector_type(4)));   // native vector: NT-load legal

// bf16 round-to-nearest-even pack of two floats -> (lo=a, hi=b)
__device__ __forceinline__ unsigned int pack_bf2(float a, float b) {
    unsigned int ua = __float_as_uint(a);
    ua += 0x7FFFu + ((ua >> 16) & 1u);
    unsigned int ub = __float_as_uint(b);
    ub += 0x7FFFu + ((ub >> 16) & 1u);
    return (ua >> 16) | (ub & 0xFFFF0000u);
}

// ---------------- GEMM body: Ybf16[32 rows x 128] = X @ W, 256 threads, 16 KB LDS ----
__device__ __forceinline__ void gemm128_body(const float* __restrict__ X,
                                             const float* __restrict__ W, unsigned int* __restrict__ Y,
                                             int row0, int tid, float* Xs) {
    const float4* X4 = (const float4*)X;
#pragma unroll
    for (int idx = tid; idx < 1024; idx += 256) {
        int r = idx & 31, c4 = idx >> 5;
        int row = row0 + r;
        float4 v = X4[(size_t)row * 32 + c4];
        Xs[(c4 * 4 + 0) * 32 + r] = v.x;
        Xs[(c4 * 4 + 1) * 32 + r] = v.y;
        Xs[(c4 * 4 + 2) * 32 + r] = v.z;
        Xs[(c4 * 4 + 3) * 32 + r] = v.w;
    }
    __syncthreads();
    int cg = tid & 31;   // cols 4cg..4cg+3
    int rg = tid >> 5;   // rows 4rg..4rg+3
    float a[4][4];
#pragma unroll
    for (int r = 0; r < 4; ++r)
#pragma unroll
        for (int c = 0; c < 4; ++c) a[r][c] = 0.f;
    const float4* W4 = (const float4*)W;
#pragma unroll 4
    for (int k = 0; k < 128; ++k) {
        float4 xv = *(const float4*)&Xs[k * 32 + rg * 4];
        float4 wv = W4[k * 32 + cg];
        float xr[4] = {xv.x, xv.y, xv.z, xv.w};
        float wc[4] = {wv.x, wv.y, wv.z, wv.w};
#pragma unroll
        for (int r = 0; r < 4; ++r)
#pragma unroll
            for (int c = 0; c < 4; ++c) a[r][c] = fmaf(xr[r], wc[c], a[r][c]);
    }
    int rbase = row0 + rg * 4;
    uint2* Y2 = (uint2*)Y;   // 32 uint2 per 128-col bf16 row
#pragma unroll
    for (int r = 0; r < 4; ++r) {
        Y2[(size_t)(rbase + r) * 32 + cg] =
            make_uint2(pack_bf2(a[r][0], a[r][1]), pack_bf2(a[r][2], a[r][3]));
    }
}

// ---------------- Pass A: interleaved GEMM0 + edge partition into node buckets ------
// Replaces 3.2M device-scope atomicAdds (non-coherent XCD L2s force every atomic to
// the fabric coherence point: ~32B RMW write each -> the measured 146MB WRITE churn)
// with: LDS histograms + ONE global atomicAdd per (bucket,block) = 306K atomics, then
// packed staging writes. Pass B finishes ELL/degrees with LDS-only atomics.
__global__ __launch_bounds__(256) void k_buildA_gemm0(const int* __restrict__ src, const int* __restrict__ dst,
                                                      int* __restrict__ curD, int* __restrict__ curS,
                                                      unsigned int* __restrict__ stagD,
                                                      unsigned short* __restrict__ stagS,
                                                      const float* __restrict__ X, const float* __restrict__ W,
                                                      unsigned int* __restrict__ Y) {
    __shared__ float Xs[128 * 32];
    int tid = threadIdx.x;
    int q = blockIdx.x / 5, rem = blockIdx.x % 5;
    if (rem) {   // GEMM block
        int g = q * 4 + (rem - 1);
        if (g < GEMMN) gemm128_body(X, W, Y, g * 32, tid, Xs);
        return;
    }
    // LDS scratch: [0..195]=histD [256..451]=histS [512..707]=baseD [768..963]=baseS
    //              [1024..1219]=locD [1280..1475]=locS
    int* sh = (int*)Xs;
    for (int i = tid; i < 1536; i += 256) sh[i] = 0;
    __syncthreads();

    const iv4* s4p = (const iv4*)src;
    const iv4* d4p = (const iv4*)dst;
    const int n4 = EE / 4;
    iv4 sv[2], dv[2];
    int have[2];
#pragma unroll
    for (int h = 0; h < 2; ++h) {
        int i4 = q * 512 + h * 256 + tid;
        have[h] = (i4 < n4);
        if (have[h]) {
            sv[h] = __builtin_nontemporal_load(&s4p[i4]);
            dv[h] = __builtin_nontemporal_load(&d4p[i4]);
        }
    }
    // histogram
#pragma unroll
    for (int h = 0; h < 2; ++h) {
        if (have[h]) {
            int ss[4] = {sv[h].x, sv[h].y, sv[h].z, sv[h].w};
            int dd[4] = {dv[h].x, dv[h].y, dv[h].z, dv[h].w};
#pragma unroll
            for (int k = 0; k < 4; ++k) {
                atomicAdd(&sh[dd[k] >> BSH], 1);
                atomicAdd(&sh[256 + (ss[k] >> BSH)], 1);
            }
        }
    }
    __syncthreads();
    if (tid < NBKT) {
        int hd = sh[tid];
        sh[512 + tid] = hd ? atomicAdd(&curD[tid], hd) : 0;
        int hs = sh[256 + tid];
        sh[768 + tid] = hs ? atomicAdd(&curS[tid], hs) : 0;
    }
    __syncthreads();
    // scatter into staging
#pragma unroll
    for (int h = 0; h < 2; ++h) {
        if (have[h]) {
            int ss[4] = {sv[h].x, sv[h].y, sv[h].z, sv[h].w};
            int dd[4] = {dv[h].x, dv[h].y, dv[h].z, dv[h].w};
#pragma unroll
            for (int k = 0; k < 4; ++k) {
                int bd = dd[k] >> BSH;
                int od = atomicAdd(&sh[1024 + bd], 1);
                stagD[(size_t)bd * CAPD + sh[512 + bd] + od] =
                    ((unsigned int)ss[k] << BSH) | (unsigned int)(dd[k] & 511);
                int bs = ss[k] >> BSH;
                int os = atomicAdd(&sh[1280 + bs], 1);
                stagS[(size_t)bs * CAPS + sh[768 + bs] + os] = (unsigned short)(ss[k] & 511);
            }
        }
    }
}

// ---------------- Pass B: per-bucket ELL + degree build, LDS atomics only ------------
// Blocks 0..NBKT-1: ELL build for dst-bucket b (128KB L2-resident region, written once).
// Blocks NBKT..2*NBKT-1: dout histogram for src-bucket b-NBKT.
__global__ __launch_bounds__(256) void k_buildB(const int* __restrict__ curD, const int* __restrict__ curS,
                                                const unsigned int* __restrict__ stagD,
                                                const unsigned short* __restrict__ stagS,
                                                int* __restrict__ din, int* __restrict__ dout,
                                                int* __restrict__ ell) {
    __shared__ int cl[512];
    int tid = threadIdx.x;
    int b = blockIdx.x;
    for (int i = tid; i < 512; i += 256) cl[i] = 0;
    __syncthreads();
    if (b < NBKT) {
        int n0 = b << BSH;
        int cnt = min(curD[b], CAPD);
        const unsigned int* sg = stagD + (size_t)b * CAPD;
        for (int i = tid; i < cnt; i += 256) {
            unsigned int v = sg[i];
            int dlow = (int)(v & 511u);
            int s = (int)(v >> BSH);
            int p = atomicAdd(&cl[dlow], 1);
            if (p < ELLW) ell[(size_t)(n0 + dlow) * ELLW + p] = s;
        }
        __syncthreads();
        for (int i = tid; i < 512; i += 256) {
            int node = n0 + i;
            if (node < NN) din[node] = cl[i];
        }
    } else {
        int bs = b - NBKT;
        int n0 = bs << BSH;
        int cnt = min(curS[bs], CAPS);
        const unsigned short* sg = stagS + (size_t)bs * CAPS;
        for (int i = tid; i < cnt; i += 256) {
            atomicAdd(&cl[sg[i]], 1);
        }
        __syncthreads();
        for (int i = tid; i < 512; i += 256) {
            int node = n0 + i;
            if (node < NN) dout[node] = cl[i];
        }
    }
}

// ---------------- fused gather + GEMM128 (layer boundary) ----------------
__global__ __launch_bounds__(256) void k_gathergemm128(const unsigned int* __restrict__ h,
                                                       const int* __restrict__ din, const int* __restrict__ dout,
                                                       const int* __restrict__ ell,
                                                       const float* __restrict__ bias,
                                                       const float* __restrict__ W,
                                                       unsigned int* __restrict__ Y, int so_mode) {
    __shared__ float Xs[128 * 36];
    int tid = threadIdx.x;
    int wv = tid >> 6, lane = tid & 63;
    int row0 = blockIdx.x * 32;
    float2 bb = ((const float2*)bias)[lane];
    for (int j8 = 0; j8 < 8; ++j8) {
        int r = wv * 8 + j8;
        int v = row0 + r;       // N = 3125*32 exactly, no bounds needed
        int dv = din[v];
        int cnt = min(dv, ELLW);
        int cl = ell[(size_t)v * ELLW + lane];
        // ELL slots >= cnt are UNINITIALIZED -> clamp before any deref
        int cls = (lane < cnt) ? cl : 0;
        float scl = 1.f;
        if (so_mode) scl = rsqrtf((float)max(1, dout[cls]));
        float sx = 0.f, sy = 0.f;
        for (int j = 0; j < cnt; j += 8) {
            int cc[8]; float mk[8]; unsigned int t[8];
#pragma unroll
            for (int k = 0; k < 8; ++k) {
                int jj = j + k;
                int jc = jj < cnt ? jj : cnt - 1;
                cc[k] = __shfl(cls, jc);
                float sw = so_mode ? __shfl(scl, jc) : 1.f;
                mk[k] = (jj < cnt) ? sw : 0.f;
            }
#pragma unroll
            for (int k = 0; k < 8; ++k) t[k] = h[(size_t)cc[k] * 64 + lane];
#pragma unroll
            for (int k = 0; k < 8; ++k) {
                float x = __uint_as_float(t[k] << 16);
                float y = __uint_as_float(t[k] & 0xFFFF0000u);
                sx = fmaf(mk[k], x, sx);
                sy = fmaf(mk[k], y, sy);
            }
        }
        float si = rsqrtf((float)max(1, dv));
        float so = rsqrtf((float)max(1, dout[v]));
        float ox = fmaxf(sx * si + bb.x, 0.f) * so;
        float oy = fmaxf(sy * si + bb.y, 0.f) * so;
        Xs[(2 * lane) * 36 + r] = ox;
        Xs[(2 * lane + 1) * 36 + r] = oy;
    }
    __syncthreads();
    int cg = tid & 31, rg = tid >> 5;
    float a[4][4];
#pragma unroll
    for (int r = 0; r < 4; ++r)
#pragma unroll
        for (int c = 0; c < 4; ++c) a[r][c] = 0.f;
    const float4* W4 = (const float4*)W;
#pragma unroll 4
    for (int k = 0; k < 128; ++k) {
        float4 xv = *(const float4*)&Xs[k * 36 + rg * 4];
        float4 wv4 = W4[k * 32 + cg];
        float xr[4] = {xv.x, xv.y, xv.z, xv.w};
        float wc[4] = {wv4.x, wv4.y, wv4.z, wv4.w};
#pragma unroll
        for (int r = 0; r < 4; ++r)
#pragma unroll
            for (int c = 0; c < 4; ++c) a[r][c] = fmaf(xr[r], wc[c], a[r][c]);
    }
    int rbase = row0 + rg * 4;
    uint2* Y2 = (uint2*)Y;
#pragma unroll
    for (int r = 0; r < 4; ++r) {
        Y2[(size_t)(rbase + r) * 32 + cg] =
            make_uint2(pack_bf2(a[r][0], a[r][1]), pack_bf2(a[r][2], a[r][3]));
    }
}

// ---------------- fused gather + GEMM[128x40] (layer 2 pre-gather transform) --------
__global__ __launch_bounds__(256) void k_gathergemm40(const unsigned int* __restrict__ h,
                                                      const int* __restrict__ din, const int* __restrict__ dout,
                                                      const int* __restrict__ ell,
                                                      const float* __restrict__ bias,
                                                      const float* __restrict__ W,
                                                      unsigned int* __restrict__ Y) {
    __shared__ float Xs[128 * 36];
    __shared__ float Os[32 * 40];
    int tid = threadIdx.x;
    int wv = tid >> 6, lane = tid & 63;
    int row0 = blockIdx.x * 32;
    float2 bb = ((const float2*)bias)[lane];
    for (int j8 = 0; j8 < 8; ++j8) {
        int r = wv * 8 + j8;
        int v = row0 + r;
        int dv = din[v];
        int cnt = min(dv, ELLW);
        int cl = ell[(size_t)v * ELLW + lane];
        int cls = (lane < cnt) ? cl : 0;
        float sx = 0.f, sy = 0.f;
        for (int j = 0; j < cnt; j += 8) {
            int cc[8]; float mk[8]; unsigned int t[8];
#pragma unroll
            for (int k = 0; k < 8; ++k) {
                int jj = j + k;
                cc[k] = __shfl(cls, jj < cnt ? jj : cnt - 1);
                mk[k] = (jj < cnt) ? 1.f : 0.f;
            }
#pragma unroll
            for (int k = 0; k < 8; ++k) t[k] = h[(size_t)cc[k] * 64 + lane];
#pragma unroll
            for (int k = 0; k < 8; ++k) {
                float x = __uint_as_float(t[k] << 16);
                float y = __uint_as_float(t[k] & 0xFFFF0000u);
                sx = fmaf(mk[k], x, sx);
                sy = fmaf(mk[k], y, sy);
            }
        }
        float si = rsqrtf((float)max(1, dv));
        float so = rsqrtf((float)max(1, dout[v]));
        float ox = fmaxf(sx * si + bb.x, 0.f) * so;
        float oy = fmaxf(sy * si + bb.y, 0.f) * so;
        Xs[(2 * lane) * 36 + r] = ox;
        Xs[(2 * lane + 1) * 36 + r] = oy;
    }
    __syncthreads();
    // gemm: thread = (row rg, 5-col group cg). W2 is 20KB -> L1-resident broadcasts.
    int rg = tid >> 3;       // 32 rows
    int cg = tid & 7;        // 8 groups x 5 cols
    float a[5] = {0.f, 0.f, 0.f, 0.f, 0.f};
    for (int k = 0; k < 128; ++k) {
        float x = Xs[k * 36 + rg];
#pragma unroll
        for (int c = 0; c < 5; ++c) a[c] = fmaf(x, W[k * 40 + cg * 5 + c], a[c]);
    }
#pragma unroll
    for (int c = 0; c < 5; ++c) Os[rg * 40 + cg * 5 + c] = a[c];
    __syncthreads();
    for (int i = tid; i < 640; i += 256) {
        int row = i / 20, pj = i % 20;
        Y[(size_t)(row0 + row) * 32 + pj] = pack_bf2(Os[row * 40 + 2 * pj], Os[row * 40 + 2 * pj + 1]);
    }
}

// ---------------- gather-aggregate (ELL), 40 cols bf16 padded-128B rows (final layer) ----
__global__ __launch_bounds__(256) void k_gather40(const unsigned short* __restrict__ h, const int* __restrict__ din,
                                                  const int* __restrict__ ell,
                                                  const float* __restrict__ b, float* __restrict__ out, int n) {
    int wv = threadIdx.x >> 6, lane = threadIdx.x & 63;
    int v = blockIdx.x * 4 + wv;
    if (v >= n) return;
    int dv = din[v];
    int cnt = min(dv, ELLW);
    int cl = ell[(size_t)v * ELLW + lane];
    int cls = (lane < cnt) ? cl : 0;
    float s = 0.f;
    for (int j = 0; j < cnt; j += 8) {
        int cc[8]; float mk[8]; unsigned short t[8];
#pragma unroll
        for (int k = 0; k < 8; ++k) {
            int jj = j + k;
            cc[k] = __shfl(cls, jj < cnt ? jj : cnt - 1);
            mk[k] = (jj < cnt) ? 1.f : 0.f;
        }
        if (lane < 40) {
#pragma unroll
            for (int k = 0; k < 8; ++k) t[k] = h[(size_t)cc[k] * 64 + lane];  // 64-short rows = 128 B
#pragma unroll
            for (int k = 0; k < 8; ++k)
                s = fmaf(mk[k], __uint_as_float((unsigned int)t[k] << 16), s);
        }
    }
    if (lane < 40) {
        out[(size_t)v * 40 + lane] = s * rsqrtf((float)max(1, dv)) + b[lane];
    }
}

extern "C" void kernel_launch(void* const* d_in, const int* in_sizes, int n_in,
                              void* d_out, int out_size, void* d_ws, size_t ws_size,
                              hipStream_t stream) {
    const float* feat = (const float*)d_in[0];
    const int*   src  = (const int*)d_in[1];
    const int*   dst  = (const int*)d_in[2];
    const float* W0   = (const float*)d_in[3];
    const float* b0   = (const float*)d_in[4];
    const float* W1   = (const float*)d_in[5];
    const float* b1   = (const float*)d_in[6];
    const float* W2   = (const float*)d_in[7];
    const float* b2   = (const float*)d_in[8];
    float* out = (float*)d_out;

    char* w = (char*)d_ws;
    int*   din       = (int*)w;    w += (size_t)NN * 4;
    int*   dout      = (int*)w;    w += (size_t)NN * 4;
    int*   curD      = (int*)w;    w += 256 * 4;                      // bucket cursors (memset'd)
    int*   curS      = (int*)w;    w += 256 * 4;
    int*   ell       = (int*)w;    w += (size_t)NN * ELLW * 4;        // 25.6 MB
    unsigned int*   stagD = (unsigned int*)w;   w += (size_t)NBKT * CAPD * 4;   // 8.0 MB
    unsigned short* stagS = (unsigned short*)w; w += (size_t)NBKT * CAPS * 2;   // 4.0 MB
    unsigned int* h2 = (unsigned int*)w; w += (size_t)NN * 128 * 2;   // bf16 rows, 25.6 MB
    unsigned int* h2b = (unsigned int*)w; w += (size_t)NN * 128 * 2;  // bf16 rows, 25.6 MB
    unsigned int* h40 = (unsigned int*)w; w += (size_t)NN * 32 * 4;   // bf16 40-col rows padded to 128 B

    // zero din, dout, bucket cursors (contiguous at base)
    (void)hipMemsetAsync(d_ws, 0, (size_t)NN * 8 + 2048, stream);

    // Pass A: interleaved GEMM0 (feat@W0 -> h2) + edge partition into buckets
    k_buildA_gemm0<<<GRID_BG, 256, 0, stream>>>(src, dst, curD, curS, stagD, stagS, feat, W0, h2);
    // Pass B: per-bucket ELL + din (blocks 0..195) and dout (blocks 196..391), LDS atomics only
    k_buildB<<<NBKT * 2, 256, 0, stream>>>(curD, curS, stagD, stagS, din, dout, ell);
    // layer 0 gather (per-neighbor so, si, b0, relu) + so-prescale + GEMM W1 -> h2b
    k_gathergemm128<<<GEMMN, 256, 0, stream>>>(h2, din, dout, ell, b0, W1, h2b, 1);
    // layer 1 gather (so folded in h2b, si, b1, relu) + so-prescale + GEMM W2 -> h40
    k_gathergemm40<<<GEMMN, 256, 0, stream>>>(h2b, din, dout, ell, b1, W2, h40);
    // final gather writes d_out
    k_gather40<<<(NN + 3) / 4, 256, 0, stream>>>((const unsigned short*)h40, din, ell, b2, out, NN);
}